// Round 14
// baseline (170.026 us; speedup 1.0000x reference)
//
#include <hip/hip_runtime.h>

#define B 8
#define C 256
#define N 4096
#define A 32

typedef __attribute__((ext_vector_type(8))) short bf16x8;
typedef __attribute__((ext_vector_type(4))) float f32x4;

__device__ __forceinline__ unsigned short f2bf(float f) {
  union { float f; unsigned int u; } x; x.f = f;
  unsigned int u = x.u;
  return (unsigned short)((u + 0x7FFFu + ((u >> 16) & 1u)) >> 16);  // RNE
}

// ---------------------------------------------------------------------------
// Prep: Wb[col][c] bf16, col 0..31 = Wq rows, col 32..63 = Wk rows.
// ---------------------------------------------------------------------------
__global__ __launch_bounds__(256) void prep_kernel(
    const float* __restrict__ Wq, const float* __restrict__ Wk,
    unsigned short* __restrict__ Wb) {
  int i = blockIdx.x * 256 + threadIdx.x;     // 64*256 = 16384
  int col = i >> 8, c = i & 255;
  float v = (col < 32) ? Wq[col * 256 + c] : Wk[(col - 32) * 256 + c];
  Wb[i] = f2bf(v);
}

// ---------------------------------------------------------------------------
// QK projection, 8-wave blocks (R10-exact): waves 0-3 = row-strips with C in
// [0,128), waves 4-7 = same strips, C in [128,256); LDS combine; fused out=x.
// ---------------------------------------------------------------------------
__global__ __launch_bounds__(512) void qk_mfma(
    const float* __restrict__ x, const unsigned short* __restrict__ Wb,
    const float* __restrict__ bq, const float* __restrict__ bk,
    unsigned short* __restrict__ Qb, unsigned short* __restrict__ Kb,
    float* __restrict__ out) {
  const int t = threadIdx.x;
  const int lane = t & 63, wid = t >> 6;          // wid 0..7
  const int wrow = wid & 3, whalf = wid >> 2;     // row-strip, C-half
  const int li = lane & 15, g = lane >> 4;
  const int row0 = (blockIdx.x * 4 + wrow) * 16;  // global row in [0, 32768)
  const int b = row0 >> 12;
  const int n0 = row0 & (N - 1);
  const int n_a = n0 + li;                        // this lane's A-row (n)

  __shared__ f32x4 lds_acc[4][4][64];             // 16 KB: [strip][tc][lane]

  const float* xb = x + (size_t)b * C * N;
  float* ob = out + (size_t)b * C * N;
  f32x4 acc[4] = {{0.f,0.f,0.f,0.f},{0.f,0.f,0.f,0.f},
                  {0.f,0.f,0.f,0.f},{0.f,0.f,0.f,0.f}};

#pragma unroll
  for (int ks = 0; ks < 4; ++ks) {                // 4 K-steps of 32 (half C)
    const int cbase = whalf * 128 + ks * 32 + g * 8;
    float av[8];
#pragma unroll
    for (int j = 0; j < 8; ++j)
      av[j] = xb[(size_t)(cbase + j) * N + n_a];  // 64B/li-group segments
    // fused residual copy: out = x
#pragma unroll
    for (int j = 0; j < 8; ++j)
      ob[(size_t)(cbase + j) * N + n_a] = av[j];
    bf16x8 afrag;
#pragma unroll
    for (int j = 0; j < 8; ++j) afrag[j] = (short)f2bf(av[j]);
#pragma unroll
    for (int tc = 0; tc < 4; ++tc) {
      const unsigned short* wp = Wb + (size_t)(tc * 16 + li) * 256 + cbase;
      bf16x8 bfrag = *(const bf16x8*)wp;          // 16B, L1-hot
      acc[tc] = __builtin_amdgcn_mfma_f32_16x16x32_bf16(afrag, bfrag,
                                                        acc[tc], 0, 0, 0);
    }
  }

  if (whalf == 1) {
#pragma unroll
    for (int tc = 0; tc < 4; ++tc) lds_acc[wrow][tc][lane] = acc[tc];
  }
  __syncthreads();
  if (whalf == 1) return;

#pragma unroll
  for (int tc = 0; tc < 4; ++tc) {
    f32x4 p = lds_acc[wrow][tc][lane];
    acc[tc][0] += p[0]; acc[tc][1] += p[1];
    acc[tc][2] += p[2]; acc[tc][3] += p[3];
  }

#pragma unroll
  for (int tc = 0; tc < 4; ++tc) {
    const int colbase = tc * 16 + li;             // 0..63
    const int a = colbase & 31;
    const float bias = (colbase < 32) ? bq[a] : bk[a];
    unsigned short* outp = (colbase < 32) ? Qb : Kb;
#pragma unroll
    for (int r = 0; r < 4; ++r) {                 // D row = g*4 + r
      const int n = n0 + g * 4 + r;
      outp[((size_t)b * N + n) * A + a] = f2bf(acc[tc][r] + bias);
    }
  }
}

// ---------------------------------------------------------------------------
// Fused scores + softmax + attention write: RECOMPUTE + 2 blocks/CU +
// PERSISTENT 4-tile blocks (grid 512 = exactly 2 resident blocks per CU,
// zero block turnaround; tile t+1 phase-1 compute overlaps tile t's nt-store
// drain inside the same block). R13 structure otherwise: zero retention,
// (1024,8) -> VGPR<=64; LDS 70.6 KB; full-line nontemporal store epilogue.
// ---------------------------------------------------------------------------
__global__ __launch_bounds__(1024, 8) void attn_mfma(
    const unsigned short* __restrict__ Qb, const unsigned short* __restrict__ Kb,
    float* __restrict__ attn) {
  const int t = threadIdx.x;
  const int lane = t & 63, wid = t >> 6;          // wid 0..15
  const int li = lane & 15, g = lane >> 4;
  const int b = blockIdx.x >> 6;                  // 64 blocks per batch
  const int rowbase = (blockIdx.x & 63) << 6;     // 64 rows per block

  __shared__ float red[16][16];                   // [row][wave]
  __shared__ float stage[16][16][68];             // 69.6 KB, +4 pad

  const unsigned short* kb = Kb + (size_t)b * N * A;

  for (int tile = 0; tile < 4; ++tile) {
    const int row0 = rowbase + tile * 16;
    __syncthreads();                              // red[] WAR across tiles

    const bf16x8 qfrag =
        *(const bf16x8*)(Qb + ((size_t)(b * N + row0 + li)) * A + g * 8);

    // ---- phase 1: row sums, zero retention ----
    float s[4] = {0.f, 0.f, 0.f, 0.f};
#pragma unroll 4
    for (int tc = 0; tc < 16; ++tc) {
      const int col = wid * 256 + tc * 16 + li;
      bf16x8 kfrag = *(const bf16x8*)(kb + (size_t)col * A + g * 8);  // L2-hot
      f32x4 z = {0.f, 0.f, 0.f, 0.f};
      f32x4 a0 =
          __builtin_amdgcn_mfma_f32_16x16x32_bf16(qfrag, kfrag, z, 0, 0, 0);
#pragma unroll
      for (int r = 0; r < 4; ++r) s[r] += __expf(a0[r]);
    }
#pragma unroll
    for (int r = 0; r < 4; ++r) {
#pragma unroll
      for (int off = 1; off < 16; off <<= 1)
        s[r] += __shfl_xor(s[r], off);            // sum over 16-lane group
    }
    if (li == 0) {
#pragma unroll
      for (int r = 0; r < 4; ++r) red[g * 4 + r][wid] = s[r];
    }
    __syncthreads();
    float inv[4];
#pragma unroll
    for (int r = 0; r < 4; ++r) {
      float v = red[g * 4 + r][li];               // wave li's partial
#pragma unroll
      for (int off = 1; off < 16; off <<= 1)
        v += __shfl_xor(v, off);
      inv[r] = __frcp_rn(v);
    }

    // ---- phase 2: recompute -> LDS stage -> full-line nt stores ----
    float* basep = attn + ((size_t)(b * N + row0)) * N + wid * 256;
#pragma unroll
    for (int j = 0; j < 4; ++j) {
#pragma unroll
      for (int tc4 = 0; tc4 < 4; ++tc4) {
        const int tc = j * 4 + tc4;
        const int col = wid * 256 + tc * 16 + li;
        bf16x8 kfrag =
            *(const bf16x8*)(kb + (size_t)col * A + g * 8);  // L2-hot
        f32x4 z = {0.f, 0.f, 0.f, 0.f};
        f32x4 acc =
            __builtin_amdgcn_mfma_f32_16x16x32_bf16(qfrag, kfrag, z, 0, 0, 0);
#pragma unroll
        for (int r = 0; r < 4; ++r)
          stage[wid][g * 4 + r][tc4 * 16 + li] = __expf(acc[r]) * inv[r];
      }
      asm volatile("s_waitcnt lgkmcnt(0)" ::: "memory");
      __builtin_amdgcn_sched_barrier(0);
#pragma unroll
      for (int i2 = 0; i2 < 4; ++i2) {
        const int row = i2 * 4 + g;
        f32x4 v = *(const f32x4*)&stage[wid][row][li * 4];
        __builtin_nontemporal_store(
            v, (f32x4*)(basep + (size_t)row * N + j * 64 + li * 4));
      }
      __builtin_amdgcn_sched_barrier(0);          // order next j's ds_writes
    }
  }
}

// ---------------------------------------------------------------------------
// v projection (gated; gamma==0 -> immediate return). 2048-block grid with
// internal n-loop (cheap empty dispatch).
// ---------------------------------------------------------------------------
__global__ __launch_bounds__(256) void v_kernel(
    const float* __restrict__ x, const float* __restrict__ Wv,
    const float* __restrict__ bv, const float* __restrict__ gamma,
    float* __restrict__ v) {
  if (gamma[0] == 0.0f) return;
  const int b = blockIdx.x >> 8;                  // 256 blocks per batch
  const int nbase = (blockIdx.x & 255) << 4;      // 16 n's per block
  const int c = threadIdx.x;
  for (int i = 0; i < 16; ++i) {
    const int n = nbase + i;
    const float* xp = x + (size_t)b * C * N + n;
    float acc = bv[c];
    for (int ci = 0; ci < C; ++ci)
      acc += xp[(size_t)ci * N] * Wv[(size_t)c * C + ci];
    v[((size_t)b * N + n) * C + c] = acc;
  }
}

// ---------------------------------------------------------------------------
// out = gamma * (attn @ v) + x (gated; gamma==0: out already holds x from
// qk_mfma -> immediate return). 2048-block grid with internal n-loop.
// ---------------------------------------------------------------------------
__global__ __launch_bounds__(256) void out_kernel(
    const float* __restrict__ x, const float* __restrict__ gamma,
    const float* __restrict__ attn, const float* __restrict__ v,
    float* __restrict__ out) {
  const float gm = gamma[0];
  if (gm == 0.0f) return;
  const int b = blockIdx.x >> 8;
  const int nbase = (blockIdx.x & 255) << 4;
  const int c = threadIdx.x;
  for (int i = 0; i < 16; ++i) {
    const int n = nbase + i;
    const float* ap = attn + ((size_t)b * N + n) * N;
    const float* vp = v + (size_t)b * N * C + c;
    float acc = 0.f;
    for (int k = 0; k < N; ++k) acc += ap[k] * vp[(size_t)k * C];
    size_t oi = ((size_t)b * C + c) * N + n;
    out[oi] = gm * acc + x[oi];
  }
}

extern "C" void kernel_launch(void* const* d_in, const int* in_sizes, int n_in,
                              void* d_out, int out_size, void* d_ws,
                              size_t ws_size, hipStream_t stream) {
  const float* x     = (const float*)d_in[0];
  const float* Wq    = (const float*)d_in[1];
  const float* bq    = (const float*)d_in[2];
  const float* Wk    = (const float*)d_in[3];
  const float* bk    = (const float*)d_in[4];
  const float* Wv    = (const float*)d_in[5];
  const float* bv    = (const float*)d_in[6];
  const float* gamma = (const float*)d_in[7];

  float* out  = (float*)d_out;                    // B*C*N
  float* attn = out + (size_t)B * C * N;          // B*N*N

  unsigned short* Qb = (unsigned short*)d_ws;            // 2 MB
  unsigned short* Kb = Qb + (size_t)B * N * A;           // 2 MB
  unsigned short* Wb = Kb + (size_t)B * N * A;           // 32 KB
  float* vbuf = (float*)(Wb + 64 * 256);                 // 33.5 MB (gated)

  prep_kernel<<<64, 256, 0, stream>>>(Wq, Wk, Wb);
  qk_mfma<<<(B * N) / 64, 512, 0, stream>>>(x, Wb, bq, bk, Qb, Kb, out);
  attn_mfma<<<B * (N / 64), 1024, 0, stream>>>(Qb, Kb, attn);
  v_kernel<<<B * (N / 16), 256, 0, stream>>>(x, Wv, bv, gamma, vbuf);
  out_kernel<<<B * (N / 16), 256, 0, stream>>>(x, gamma, attn, vbuf, out);
}

// Round 15
// 146.807 us; speedup vs baseline: 1.1582x; 1.1582x over previous
//
#include <hip/hip_runtime.h>

#define B 8
#define C 256
#define N 4096
#define A 32

typedef __attribute__((ext_vector_type(8))) short bf16x8;
typedef __attribute__((ext_vector_type(4))) float f32x4;

__device__ __forceinline__ unsigned short f2bf(float f) {
  union { float f; unsigned int u; } x; x.f = f;
  unsigned int u = x.u;
  return (unsigned short)((u + 0x7FFFu + ((u >> 16) & 1u)) >> 16);  // RNE
}

// ---------------------------------------------------------------------------
// Prep: Wb[col][c] bf16, col 0..31 = Wq rows, col 32..63 = Wk rows.
// ---------------------------------------------------------------------------
__global__ __launch_bounds__(256) void prep_kernel(
    const float* __restrict__ Wq, const float* __restrict__ Wk,
    unsigned short* __restrict__ Wb) {
  int i = blockIdx.x * 256 + threadIdx.x;     // 64*256 = 16384
  int col = i >> 8, c = i & 255;
  float v = (col < 32) ? Wq[col * 256 + c] : Wk[(col - 32) * 256 + c];
  Wb[i] = f2bf(v);
}

// ---------------------------------------------------------------------------
// QK projection, 8-wave blocks (R10-exact): waves 0-3 = row-strips with C in
// [0,128), waves 4-7 = same strips, C in [128,256); LDS combine; fused out=x.
// ---------------------------------------------------------------------------
__global__ __launch_bounds__(512) void qk_mfma(
    const float* __restrict__ x, const unsigned short* __restrict__ Wb,
    const float* __restrict__ bq, const float* __restrict__ bk,
    unsigned short* __restrict__ Qb, unsigned short* __restrict__ Kb,
    float* __restrict__ out) {
  const int t = threadIdx.x;
  const int lane = t & 63, wid = t >> 6;          // wid 0..7
  const int wrow = wid & 3, whalf = wid >> 2;     // row-strip, C-half
  const int li = lane & 15, g = lane >> 4;
  const int row0 = (blockIdx.x * 4 + wrow) * 16;  // global row in [0, 32768)
  const int b = row0 >> 12;
  const int n0 = row0 & (N - 1);
  const int n_a = n0 + li;                        // this lane's A-row (n)

  __shared__ f32x4 lds_acc[4][4][64];             // 16 KB: [strip][tc][lane]

  const float* xb = x + (size_t)b * C * N;
  float* ob = out + (size_t)b * C * N;
  f32x4 acc[4] = {{0.f,0.f,0.f,0.f},{0.f,0.f,0.f,0.f},
                  {0.f,0.f,0.f,0.f},{0.f,0.f,0.f,0.f}};

#pragma unroll
  for (int ks = 0; ks < 4; ++ks) {                // 4 K-steps of 32 (half C)
    const int cbase = whalf * 128 + ks * 32 + g * 8;
    float av[8];
#pragma unroll
    for (int j = 0; j < 8; ++j)
      av[j] = xb[(size_t)(cbase + j) * N + n_a];  // 64B/li-group segments
    // fused residual copy: out = x
#pragma unroll
    for (int j = 0; j < 8; ++j)
      ob[(size_t)(cbase + j) * N + n_a] = av[j];
    bf16x8 afrag;
#pragma unroll
    for (int j = 0; j < 8; ++j) afrag[j] = (short)f2bf(av[j]);
#pragma unroll
    for (int tc = 0; tc < 4; ++tc) {
      const unsigned short* wp = Wb + (size_t)(tc * 16 + li) * 256 + cbase;
      bf16x8 bfrag = *(const bf16x8*)wp;          // 16B, L1-hot
      acc[tc] = __builtin_amdgcn_mfma_f32_16x16x32_bf16(afrag, bfrag,
                                                        acc[tc], 0, 0, 0);
    }
  }

  if (whalf == 1) {
#pragma unroll
    for (int tc = 0; tc < 4; ++tc) lds_acc[wrow][tc][lane] = acc[tc];
  }
  __syncthreads();
  if (whalf == 1) return;

#pragma unroll
  for (int tc = 0; tc < 4; ++tc) {
    f32x4 p = lds_acc[wrow][tc][lane];
    acc[tc][0] += p[0]; acc[tc][1] += p[1];
    acc[tc][2] += p[2]; acc[tc][3] += p[3];
  }

#pragma unroll
  for (int tc = 0; tc < 4; ++tc) {
    const int colbase = tc * 16 + li;             // 0..63
    const int a = colbase & 31;
    const float bias = (colbase < 32) ? bq[a] : bk[a];
    unsigned short* outp = (colbase < 32) ? Qb : Kb;
#pragma unroll
    for (int r = 0; r < 4; ++r) {                 // D row = g*4 + r
      const int n = n0 + g * 4 + r;
      outp[((size_t)b * N + n) * A + a] = f2bf(acc[tc][r] + bias);
    }
  }
}

// ---------------------------------------------------------------------------
// Fused scores + softmax + attention write: RECOMPUTE + 2 blocks/CU +
// persistent 4-tile blocks with NO vmcnt drains inside the loop:
// red[2][][] double-buffered by tile parity; the single per-tile sync is a
// raw s_barrier preceded by lgkmcnt(0) ONLY -- nt stores from tile t drain
// under tile t+1's phase-1 compute (fix for R14's __syncthreads vmcnt(0)
// flush). Otherwise R13-identical: zero retention, (1024,8) -> VGPR<=64,
// full-line nontemporal store epilogue via wave-private LDS staging.
// ---------------------------------------------------------------------------
__global__ __launch_bounds__(1024, 8) void attn_mfma(
    const unsigned short* __restrict__ Qb, const unsigned short* __restrict__ Kb,
    float* __restrict__ attn) {
  const int t = threadIdx.x;
  const int lane = t & 63, wid = t >> 6;          // wid 0..15
  const int li = lane & 15, g = lane >> 4;
  const int b = blockIdx.x >> 6;                  // 64 blocks per batch
  const int rowbase = (blockIdx.x & 63) << 6;     // 64 rows per block

  __shared__ float red[2][16][16];                // [tile&1][row][wave]
  __shared__ float stage[16][16][68];             // 69.6 KB, +4 pad

  const unsigned short* kb = Kb + (size_t)b * N * A;

  for (int tile = 0; tile < 4; ++tile) {
    const int p = tile & 1;
    const int row0 = rowbase + tile * 16;

    const bf16x8 qfrag =
        *(const bf16x8*)(Qb + ((size_t)(b * N + row0 + li)) * A + g * 8);

    // ---- phase 1: row sums, zero retention ----
    float s[4] = {0.f, 0.f, 0.f, 0.f};
#pragma unroll 4
    for (int tc = 0; tc < 16; ++tc) {
      const int col = wid * 256 + tc * 16 + li;
      bf16x8 kfrag = *(const bf16x8*)(kb + (size_t)col * A + g * 8);  // L2-hot
      f32x4 z = {0.f, 0.f, 0.f, 0.f};
      f32x4 a0 =
          __builtin_amdgcn_mfma_f32_16x16x32_bf16(qfrag, kfrag, z, 0, 0, 0);
#pragma unroll
      for (int r = 0; r < 4; ++r) s[r] += __expf(a0[r]);
    }
#pragma unroll
    for (int r = 0; r < 4; ++r) {
#pragma unroll
      for (int off = 1; off < 16; off <<= 1)
        s[r] += __shfl_xor(s[r], off);            // sum over 16-lane group
    }
    if (li == 0) {
#pragma unroll
      for (int r = 0; r < 4; ++r) red[p][g * 4 + r][wid] = s[r];
    }
    // single per-tile sync: LDS-only wait, nt stores stay in flight
    asm volatile("s_waitcnt lgkmcnt(0)" ::: "memory");
    __builtin_amdgcn_sched_barrier(0);
    __builtin_amdgcn_s_barrier();
    __builtin_amdgcn_sched_barrier(0);

    float inv[4];
#pragma unroll
    for (int r = 0; r < 4; ++r) {
      float v = red[p][g * 4 + r][li];            // wave li's partial
#pragma unroll
      for (int off = 1; off < 16; off <<= 1)
        v += __shfl_xor(v, off);
      inv[r] = __frcp_rn(v);
    }

    // ---- phase 2: recompute -> LDS stage -> full-line nt stores ----
    float* basep = attn + ((size_t)(b * N + row0)) * N + wid * 256;
#pragma unroll
    for (int j = 0; j < 4; ++j) {
#pragma unroll
      for (int tc4 = 0; tc4 < 4; ++tc4) {
        const int tc = j * 4 + tc4;
        const int col = wid * 256 + tc * 16 + li;
        bf16x8 kfrag =
            *(const bf16x8*)(kb + (size_t)col * A + g * 8);  // L2-hot
        f32x4 z = {0.f, 0.f, 0.f, 0.f};
        f32x4 acc =
            __builtin_amdgcn_mfma_f32_16x16x32_bf16(qfrag, kfrag, z, 0, 0, 0);
#pragma unroll
        for (int r = 0; r < 4; ++r)
          stage[wid][g * 4 + r][tc4 * 16 + li] = __expf(acc[r]) * inv[r];
      }
      asm volatile("s_waitcnt lgkmcnt(0)" ::: "memory");
      __builtin_amdgcn_sched_barrier(0);
#pragma unroll
      for (int i2 = 0; i2 < 4; ++i2) {
        const int row = i2 * 4 + g;
        f32x4 v = *(const f32x4*)&stage[wid][row][li * 4];
        __builtin_nontemporal_store(
            v, (f32x4*)(basep + (size_t)row * N + j * 64 + li * 4));
      }
      __builtin_amdgcn_sched_barrier(0);          // order next j's ds_writes
    }
  }
}

// ---------------------------------------------------------------------------
// v projection (gated; gamma==0 -> immediate return). 2048-block grid with
// internal n-loop (cheap empty dispatch).
// ---------------------------------------------------------------------------
__global__ __launch_bounds__(256) void v_kernel(
    const float* __restrict__ x, const float* __restrict__ Wv,
    const float* __restrict__ bv, const float* __restrict__ gamma,
    float* __restrict__ v) {
  if (gamma[0] == 0.0f) return;
  const int b = blockIdx.x >> 8;                  // 256 blocks per batch
  const int nbase = (blockIdx.x & 255) << 4;      // 16 n's per block
  const int c = threadIdx.x;
  for (int i = 0; i < 16; ++i) {
    const int n = nbase + i;
    const float* xp = x + (size_t)b * C * N + n;
    float acc = bv[c];
    for (int ci = 0; ci < C; ++ci)
      acc += xp[(size_t)ci * N] * Wv[(size_t)c * C + ci];
    v[((size_t)b * N + n) * C + c] = acc;
  }
}

// ---------------------------------------------------------------------------
// out = gamma * (attn @ v) + x (gated; gamma==0: out already holds x from
// qk_mfma -> immediate return). 2048-block grid with internal n-loop.
// ---------------------------------------------------------------------------
__global__ __launch_bounds__(256) void out_kernel(
    const float* __restrict__ x, const float* __restrict__ gamma,
    const float* __restrict__ attn, const float* __restrict__ v,
    float* __restrict__ out) {
  const float gm = gamma[0];
  if (gm == 0.0f) return;
  const int b = blockIdx.x >> 8;
  const int nbase = (blockIdx.x & 255) << 4;
  const int c = threadIdx.x;
  for (int i = 0; i < 16; ++i) {
    const int n = nbase + i;
    const float* ap = attn + ((size_t)b * N + n) * N;
    const float* vp = v + (size_t)b * N * C + c;
    float acc = 0.f;
    for (int k = 0; k < N; ++k) acc += ap[k] * vp[(size_t)k * C];
    size_t oi = ((size_t)b * C + c) * N + n;
    out[oi] = gm * acc + x[oi];
  }
}

extern "C" void kernel_launch(void* const* d_in, const int* in_sizes, int n_in,
                              void* d_out, int out_size, void* d_ws,
                              size_t ws_size, hipStream_t stream) {
  const float* x     = (const float*)d_in[0];
  const float* Wq    = (const float*)d_in[1];
  const float* bq    = (const float*)d_in[2];
  const float* Wk    = (const float*)d_in[3];
  const float* bk    = (const float*)d_in[4];
  const float* Wv    = (const float*)d_in[5];
  const float* bv    = (const float*)d_in[6];
  const float* gamma = (const float*)d_in[7];

  float* out  = (float*)d_out;                    // B*C*N
  float* attn = out + (size_t)B * C * N;          // B*N*N

  unsigned short* Qb = (unsigned short*)d_ws;            // 2 MB
  unsigned short* Kb = Qb + (size_t)B * N * A;           // 2 MB
  unsigned short* Wb = Kb + (size_t)B * N * A;           // 32 KB
  float* vbuf = (float*)(Wb + 64 * 256);                 // 33.5 MB (gated)

  prep_kernel<<<64, 256, 0, stream>>>(Wq, Wk, Wb);
  qk_mfma<<<(B * N) / 64, 512, 0, stream>>>(x, Wb, bq, bk, Qb, Kb, out);
  attn_mfma<<<B * (N / 64), 1024, 0, stream>>>(Qb, Kb, attn);
  v_kernel<<<B * (N / 16), 256, 0, stream>>>(x, Wv, bv, gamma, vbuf);
  out_kernel<<<B * (N / 16), 256, 0, stream>>>(x, gamma, attn, vbuf, out);
}

// Round 16
// 127.618 us; speedup vs baseline: 1.3323x; 1.1504x over previous
//
#include <hip/hip_runtime.h>

#define B 8
#define C 256
#define N 4096
#define A 32

typedef __attribute__((ext_vector_type(8))) short bf16x8;
typedef __attribute__((ext_vector_type(4))) float f32x4;

__device__ __forceinline__ unsigned short f2bf(float f) {
  union { float f; unsigned int u; } x; x.f = f;
  unsigned int u = x.u;
  return (unsigned short)((u + 0x7FFFu + ((u >> 16) & 1u)) >> 16);  // RNE
}

// ---------------------------------------------------------------------------
// Prep: Wb[col][c] bf16, col 0..31 = Wq rows, col 32..63 = Wk rows.
// ---------------------------------------------------------------------------
__global__ __launch_bounds__(256) void prep_kernel(
    const float* __restrict__ Wq, const float* __restrict__ Wk,
    unsigned short* __restrict__ Wb) {
  int i = blockIdx.x * 256 + threadIdx.x;     // 64*256 = 16384
  int col = i >> 8, c = i & 255;
  float v = (col < 32) ? Wq[col * 256 + c] : Wk[(col - 32) * 256 + c];
  Wb[i] = f2bf(v);
}

// ---------------------------------------------------------------------------
// QK projection, 8-wave blocks (R10-exact): waves 0-3 = row-strips with C in
// [0,128), waves 4-7 = same strips, C in [128,256); LDS combine; fused out=x.
// ---------------------------------------------------------------------------
__global__ __launch_bounds__(512) void qk_mfma(
    const float* __restrict__ x, const unsigned short* __restrict__ Wb,
    const float* __restrict__ bq, const float* __restrict__ bk,
    unsigned short* __restrict__ Qb, unsigned short* __restrict__ Kb,
    float* __restrict__ out) {
  const int t = threadIdx.x;
  const int lane = t & 63, wid = t >> 6;          // wid 0..7
  const int wrow = wid & 3, whalf = wid >> 2;     // row-strip, C-half
  const int li = lane & 15, g = lane >> 4;
  const int row0 = (blockIdx.x * 4 + wrow) * 16;  // global row in [0, 32768)
  const int b = row0 >> 12;
  const int n0 = row0 & (N - 1);
  const int n_a = n0 + li;                        // this lane's A-row (n)

  __shared__ f32x4 lds_acc[4][4][64];             // 16 KB: [strip][tc][lane]

  const float* xb = x + (size_t)b * C * N;
  float* ob = out + (size_t)b * C * N;
  f32x4 acc[4] = {{0.f,0.f,0.f,0.f},{0.f,0.f,0.f,0.f},
                  {0.f,0.f,0.f,0.f},{0.f,0.f,0.f,0.f}};

#pragma unroll
  for (int ks = 0; ks < 4; ++ks) {                // 4 K-steps of 32 (half C)
    const int cbase = whalf * 128 + ks * 32 + g * 8;
    float av[8];
#pragma unroll
    for (int j = 0; j < 8; ++j)
      av[j] = xb[(size_t)(cbase + j) * N + n_a];  // 64B/li-group segments
    // fused residual copy: out = x
#pragma unroll
    for (int j = 0; j < 8; ++j)
      ob[(size_t)(cbase + j) * N + n_a] = av[j];
    bf16x8 afrag;
#pragma unroll
    for (int j = 0; j < 8; ++j) afrag[j] = (short)f2bf(av[j]);
#pragma unroll
    for (int tc = 0; tc < 4; ++tc) {
      const unsigned short* wp = Wb + (size_t)(tc * 16 + li) * 256 + cbase;
      bf16x8 bfrag = *(const bf16x8*)wp;          // 16B, L1-hot
      acc[tc] = __builtin_amdgcn_mfma_f32_16x16x32_bf16(afrag, bfrag,
                                                        acc[tc], 0, 0, 0);
    }
  }

  if (whalf == 1) {
#pragma unroll
    for (int tc = 0; tc < 4; ++tc) lds_acc[wrow][tc][lane] = acc[tc];
  }
  __syncthreads();
  if (whalf == 1) return;

#pragma unroll
  for (int tc = 0; tc < 4; ++tc) {
    f32x4 p = lds_acc[wrow][tc][lane];
    acc[tc][0] += p[0]; acc[tc][1] += p[1];
    acc[tc][2] += p[2]; acc[tc][3] += p[3];
  }

#pragma unroll
  for (int tc = 0; tc < 4; ++tc) {
    const int colbase = tc * 16 + li;             // 0..63
    const int a = colbase & 31;
    const float bias = (colbase < 32) ? bq[a] : bk[a];
    unsigned short* outp = (colbase < 32) ? Qb : Kb;
#pragma unroll
    for (int r = 0; r < 4; ++r) {                 // D row = g*4 + r
      const int n = n0 + g * 4 + r;
      outp[((size_t)b * N + n) * A + a] = f2bf(acc[tc][r] + bias);
    }
  }
}

// ---------------------------------------------------------------------------
// Fused scores + softmax + attention write. R13 structure (grid 2048, one
// 16-row tile/block, recompute, 2 blocks/CU) with ONE change: block-wide
// staged drain. Per 1024-col quarter, all waves stage exp*inv into
// stage[16][1028] (stride: scalar writes 2-way/free, 16B-aligned reads),
// lgkm-only barrier, then wave w drains row w with 4x 1KB-CONTIGUOUS nt
// stores (vs 4x256B@16KB-stride before). nt stores stay in flight across
// the raw barriers.
// ---------------------------------------------------------------------------
__global__ __launch_bounds__(1024, 8) void attn_mfma(
    const unsigned short* __restrict__ Qb, const unsigned short* __restrict__ Kb,
    float* __restrict__ attn) {
  const int t = threadIdx.x;
  const int lane = t & 63, wid = t >> 6;          // wid 0..15
  const int li = lane & 15, g = lane >> 4;
  const int b = blockIdx.x >> 8;
  const int row0 = (blockIdx.x & 255) << 4;

  __shared__ float red[16][16];                   // [row][wave]
  __shared__ float stage[16][1028];               // 64.3 KB block-wide

  const bf16x8 qfrag =
      *(const bf16x8*)(Qb + ((size_t)(b * N + row0 + li)) * A + g * 8);
  const unsigned short* kb = Kb + (size_t)b * N * A;

  // ---- phase 1: row sums, zero retention ----
  float s[4] = {0.f, 0.f, 0.f, 0.f};
#pragma unroll 4
  for (int tc = 0; tc < 16; ++tc) {
    const int col = wid * 256 + tc * 16 + li;
    bf16x8 kfrag = *(const bf16x8*)(kb + (size_t)col * A + g * 8);  // L2-hot
    f32x4 z = {0.f, 0.f, 0.f, 0.f};
    f32x4 a0 =
        __builtin_amdgcn_mfma_f32_16x16x32_bf16(qfrag, kfrag, z, 0, 0, 0);
#pragma unroll
    for (int r = 0; r < 4; ++r) s[r] += __expf(a0[r]);
  }
#pragma unroll
  for (int r = 0; r < 4; ++r) {
#pragma unroll
    for (int off = 1; off < 16; off <<= 1)
      s[r] += __shfl_xor(s[r], off);              // sum over 16-lane group
  }
  if (li == 0) {
#pragma unroll
    for (int r = 0; r < 4; ++r) red[g * 4 + r][wid] = s[r];
  }
  __syncthreads();
  float inv[4];
#pragma unroll
  for (int r = 0; r < 4; ++r) {
    float v = red[g * 4 + r][li];                 // wave li's partial
#pragma unroll
    for (int off = 1; off < 16; off <<= 1)
      v += __shfl_xor(v, off);
    inv[r] = __frcp_rn(v);
  }

  // ---- phase 2: recompute -> block-wide stage -> contiguous nt drain ----
  float* rowp = attn + ((size_t)(b * N + row0 + wid)) * N;  // wave's row
  for (int q = 0; q < 4; ++q) {
    // compute & stage: wave wid owns cols q*1024 + wid*64 .. +64
#pragma unroll
    for (int tc = 0; tc < 4; ++tc) {
      const int col = q * 1024 + wid * 64 + tc * 16 + li;
      bf16x8 kfrag = *(const bf16x8*)(kb + (size_t)col * A + g * 8);  // L2-hot
      f32x4 z = {0.f, 0.f, 0.f, 0.f};
      f32x4 acc =
          __builtin_amdgcn_mfma_f32_16x16x32_bf16(qfrag, kfrag, z, 0, 0, 0);
#pragma unroll
      for (int r = 0; r < 4; ++r)
        stage[g * 4 + r][wid * 64 + tc * 16 + li] = __expf(acc[r]) * inv[r];
    }
    // barrier A: stage visible block-wide (LDS-only wait, stores in flight)
    asm volatile("s_waitcnt lgkmcnt(0)" ::: "memory");
    __builtin_amdgcn_sched_barrier(0);
    __builtin_amdgcn_s_barrier();
    __builtin_amdgcn_sched_barrier(0);
    // drain: wave wid stores row (row0+wid), 4 x 1KB contiguous nt
#pragma unroll
    for (int k = 0; k < 4; ++k) {
      f32x4 v = *(const f32x4*)&stage[wid][k * 256 + lane * 4];
      __builtin_nontemporal_store(
          v, (f32x4*)(rowp + q * 1024 + k * 256 + lane * 4));
    }
    // barrier B: all ds_reads done -> stage reusable next quarter
    asm volatile("s_waitcnt lgkmcnt(0)" ::: "memory");
    __builtin_amdgcn_sched_barrier(0);
    __builtin_amdgcn_s_barrier();
    __builtin_amdgcn_sched_barrier(0);
  }
}

// ---------------------------------------------------------------------------
// v projection (gated; gamma==0 -> immediate return). 2048-block grid with
// internal n-loop (cheap empty dispatch).
// ---------------------------------------------------------------------------
__global__ __launch_bounds__(256) void v_kernel(
    const float* __restrict__ x, const float* __restrict__ Wv,
    const float* __restrict__ bv, const float* __restrict__ gamma,
    float* __restrict__ v) {
  if (gamma[0] == 0.0f) return;
  const int b = blockIdx.x >> 8;                  // 256 blocks per batch
  const int nbase = (blockIdx.x & 255) << 4;      // 16 n's per block
  const int c = threadIdx.x;
  for (int i = 0; i < 16; ++i) {
    const int n = nbase + i;
    const float* xp = x + (size_t)b * C * N + n;
    float acc = bv[c];
    for (int ci = 0; ci < C; ++ci)
      acc += xp[(size_t)ci * N] * Wv[(size_t)c * C + ci];
    v[((size_t)b * N + n) * C + c] = acc;
  }
}

// ---------------------------------------------------------------------------
// out = gamma * (attn @ v) + x (gated; gamma==0: out already holds x from
// qk_mfma -> immediate return). 2048-block grid with internal n-loop.
// ---------------------------------------------------------------------------
__global__ __launch_bounds__(256) void out_kernel(
    const float* __restrict__ x, const float* __restrict__ gamma,
    const float* __restrict__ attn, const float* __restrict__ v,
    float* __restrict__ out) {
  const float gm = gamma[0];
  if (gm == 0.0f) return;
  const int b = blockIdx.x >> 8;
  const int nbase = (blockIdx.x & 255) << 4;
  const int c = threadIdx.x;
  for (int i = 0; i < 16; ++i) {
    const int n = nbase + i;
    const float* ap = attn + ((size_t)b * N + n) * N;
    const float* vp = v + (size_t)b * N * C + c;
    float acc = 0.f;
    for (int k = 0; k < N; ++k) acc += ap[k] * vp[(size_t)k * C];
    size_t oi = ((size_t)b * C + c) * N + n;
    out[oi] = gm * acc + x[oi];
  }
}

extern "C" void kernel_launch(void* const* d_in, const int* in_sizes, int n_in,
                              void* d_out, int out_size, void* d_ws,
                              size_t ws_size, hipStream_t stream) {
  const float* x     = (const float*)d_in[0];
  const float* Wq    = (const float*)d_in[1];
  const float* bq    = (const float*)d_in[2];
  const float* Wk    = (const float*)d_in[3];
  const float* bk    = (const float*)d_in[4];
  const float* Wv    = (const float*)d_in[5];
  const float* bv    = (const float*)d_in[6];
  const float* gamma = (const float*)d_in[7];

  float* out  = (float*)d_out;                    // B*C*N
  float* attn = out + (size_t)B * C * N;          // B*N*N

  unsigned short* Qb = (unsigned short*)d_ws;            // 2 MB
  unsigned short* Kb = Qb + (size_t)B * N * A;           // 2 MB
  unsigned short* Wb = Kb + (size_t)B * N * A;           // 32 KB
  float* vbuf = (float*)(Wb + 64 * 256);                 // 33.5 MB (gated)

  prep_kernel<<<64, 256, 0, stream>>>(Wq, Wk, Wb);
  qk_mfma<<<(B * N) / 64, 512, 0, stream>>>(x, Wb, bq, bk, Qb, Kb, out);
  attn_mfma<<<B * (N / 16), 1024, 0, stream>>>(Qb, Kb, attn);
  v_kernel<<<B * (N / 16), 256, 0, stream>>>(x, Wv, bv, gamma, vbuf);
  out_kernel<<<B * (N / 16), 256, 0, stream>>>(x, gamma, attn, vbuf, out);
}